// Round 1
// baseline (691.323 us; speedup 1.0000x reference)
//
#include <hip/hip_runtime.h>

#define Bn 16
#define Cn 20
#define Hn 512
#define Wn 512
#define HWn (Hn*Wn)

// Mask planes, fully rewritten every kernel_launch call.
__device__ unsigned char g_a1[(size_t)Bn*HWn];
__device__ unsigned char g_a2[(size_t)Bn*HWn];

// Step-1 mask (fall_left=True, shift_w=+1):
// a1[h,w] = (ch0[h,w]==3) & (d[h,w-1]-d[h,w] >= 0) & (d[h-1,w]-d[h,w] < 0) & (d[h-1,w-1]-d[h,w] < 0)
__global__ __launch_bounds__(256) void mask1_kernel(const float* __restrict__ world) {
    int idx = blockIdx.x * 256 + threadIdx.x;           // over Bn*Hn*Wn (2^22)
    int w = idx & (Wn - 1);
    int h = (idx >> 9) & (Hn - 1);
    int b = idx >> 18;
    const float* e = world + (size_t)b * Cn * HWn;      // channel 0
    const float* d = e + HWn;                           // channel 1
    int wm = (w - 1) & (Wn - 1);
    int hm = (h - 1) & (Hn - 1);
    float dc  = d[h  * Wn + w];
    float df  = d[h  * Wn + wm];
    float da  = d[hm * Wn + w];
    float dfa = d[hm * Wn + wm];
    bool a = (e[h * Wn + w] == 3.0f) & (df - dc >= 0.0f) & (da - dc < 0.0f) & (dfa - dc < 0.0f);
    g_a1[idx] = (unsigned char)a;
}

// Intermediate (post-step-1) value of plane p at (r, wc), exact reference semantics:
// a=a1[r,wc], b=a1[r+1,wc]; {p[r], p[r-1], p[r+1], p[r-1]+p[r+1]}
__device__ __forceinline__ float stepval(const float* __restrict__ p,
                                         const unsigned char* __restrict__ a1p,
                                         int r, int wc) {
    int rm = (r - 1) & (Hn - 1), rp = (r + 1) & (Hn - 1);
    unsigned char a  = a1p[r  * Wn + wc];
    unsigned char bb = a1p[rp * Wn + wc];
    float v;
    if (a)       { v = p[rm * Wn + wc]; if (bb) v += p[rp * Wn + wc]; }
    else if (bb) { v = p[rp * Wn + wc]; }
    else         { v = p[r  * Wn + wc]; }
    return v;
}

// Step-2 mask (fall_left=False, shift_w=-1), computed from on-the-fly intermediates:
// a2[h,w] = (I0[h,w]==3) & (I1[h,w+1]-I1[h,w] >= 0) & (I1[h-1,w]-I1[h,w] < 0) & (I1[h-1,w+1]-I1[h,w] < 0)
__global__ __launch_bounds__(256) void mask2_kernel(const float* __restrict__ world) {
    int idx = blockIdx.x * 256 + threadIdx.x;
    int w = idx & (Wn - 1);
    int h = (idx >> 9) & (Hn - 1);
    int b = idx >> 18;
    const float* e = world + (size_t)b * Cn * HWn;
    const float* d = e + HWn;
    const unsigned char* a1p = g_a1 + (size_t)b * HWn;
    int wp = (w + 1) & (Wn - 1);
    int hm = (h - 1) & (Hn - 1);
    float I0   = stepval(e, a1p, h,  w);
    float I1c  = stepval(d, a1p, h,  w);
    float I1f  = stepval(d, a1p, h,  wp);
    float I1a  = stepval(d, a1p, hm, w);
    float I1fa = stepval(d, a1p, hm, wp);
    bool a = (I0 == 3.0f) & (I1f - I1c >= 0.0f) & (I1a - I1c < 0.0f) & (I1fa - I1c < 0.0f);
    g_a2[idx] = (unsigned char)a;
}

// Final: composite 5-row coefficients per pixel, applied to all 20 channels.
// out[c,h,w] = sum_{k=-2..2} ck * world[c,h+k,w]
__global__ __launch_bounds__(256) void final_kernel(const float* __restrict__ world,
                                                    float* __restrict__ out) {
    int idx = blockIdx.x * 256 + threadIdx.x;           // over Bn*Hn*(Wn/4) (2^20)
    int wq = idx & (Wn / 4 - 1);                        // 0..127
    int h  = (idx >> 7) & (Hn - 1);
    int b  = idx >> 16;
    int w  = wq * 4;

    const unsigned char* a1p = g_a1 + (size_t)b * HWn;
    const unsigned char* a2p = g_a2 + (size_t)b * HWn;
    int hm2 = (h - 2) & (Hn - 1), hm1 = (h - 1) & (Hn - 1);
    int hp1 = (h + 1) & (Hn - 1), hp2 = (h + 2) & (Hn - 1);

    float cm2[4], cm1[4], c0[4], cp1[4], cp2[4];
#pragma unroll
    for (int j = 0; j < 4; j++) {
        int wc = w + j;
        float r_m1 = (float)a1p[hm1 * Wn + wc];
        float r_0  = (float)a1p[h   * Wn + wc];
        float r_p1 = (float)a1p[hp1 * Wn + wc];
        float r_p2 = (float)a1p[hp2 * Wn + wc];
        float s0 = (float)a2p[h   * Wn + wc];
        float s1 = (float)a2p[hp1 * Wn + wc];
        float A2m = s0, A2p = s1, A2z = (1.f - s0) * (1.f - s1);
        // I[h-1] uses a1[h-1] (above) and a1[h] (below); I[h]: a1[h], a1[h+1]; I[h+1]: a1[h+1], a1[h+2]
        cm2[j] = A2m * r_m1;
        cm1[j] = A2m * (1.f - r_m1) * (1.f - r_0) + A2z * r_0;
        c0[j]  = A2m * r_0 + A2z * (1.f - r_0) * (1.f - r_p1) + A2p * r_p1;
        cp1[j] = A2z * r_p1 + A2p * (1.f - r_p1) * (1.f - r_p2);
        cp2[j] = A2p * r_p2;
    }

    const float* base  = world + (size_t)b * Cn * HWn;
    float*       obase = out   + (size_t)b * Cn * HWn;
#pragma unroll 4
    for (int c = 0; c < Cn; c++) {
        const float* p = base + (size_t)c * HWn;
        float4 x_m2 = *(const float4*)(p + hm2 * Wn + w);
        float4 x_m1 = *(const float4*)(p + hm1 * Wn + w);
        float4 x_0  = *(const float4*)(p + h   * Wn + w);
        float4 x_p1 = *(const float4*)(p + hp1 * Wn + w);
        float4 x_p2 = *(const float4*)(p + hp2 * Wn + w);
        float4 r;
        r.x = cm2[0]*x_m2.x + cm1[0]*x_m1.x + c0[0]*x_0.x + cp1[0]*x_p1.x + cp2[0]*x_p2.x;
        r.y = cm2[1]*x_m2.y + cm1[1]*x_m1.y + c0[1]*x_0.y + cp1[1]*x_p1.y + cp2[1]*x_p2.y;
        r.z = cm2[2]*x_m2.z + cm1[2]*x_m1.z + c0[2]*x_0.z + cp1[2]*x_p1.z + cp2[2]*x_p2.z;
        r.w = cm2[3]*x_m2.w + cm1[3]*x_m1.w + c0[3]*x_0.w + cp1[3]*x_p1.w + cp2[3]*x_p2.w;
        *(float4*)(obase + (size_t)c * HWn + h * Wn + w) = r;
    }
}

extern "C" void kernel_launch(void* const* d_in, const int* in_sizes, int n_in,
                              void* d_out, int out_size, void* d_ws, size_t ws_size,
                              hipStream_t stream) {
    const float* world = (const float*)d_in[0];   // (16,20,512,512) fp32; rand_* inputs unused
    float* out = (float*)d_out;

    mask1_kernel<<<(Bn * HWn) / 256, 256, 0, stream>>>(world);
    mask2_kernel<<<(Bn * HWn) / 256, 256, 0, stream>>>(world);
    final_kernel<<<(Bn * Hn * (Wn / 4)) / 256, 256, 0, stream>>>(world, out);
}